// Round 1
// baseline (5273.359 us; speedup 1.0000x reference)
//
#include <hip/hip_runtime.h>
#include <math.h>

#define VOCAB  50257
#define DM     256
#define INDIM  64
#define OUTDIM 64
#define NROWS  4096
#define SEQ    1024
#define RPB    4      // token rows per block in the fused kernel

// ---------------------------------------------------------------------------
// Kernel 1: h = x @ enc_w^T + enc_b + wpe[s]; h = LN(h)*g+b; store h/16 (folds
// the 1/sqrt(256) logit scale). One block per token row, thread d owns h[d].
// ---------------------------------------------------------------------------
__global__ __launch_bounds__(256) void encode_ln_kernel(
    const float* __restrict__ x, const float* __restrict__ enc_w,
    const float* __restrict__ enc_b, const float* __restrict__ wpe,
    const float* __restrict__ ln_g, const float* __restrict__ ln_b,
    float* __restrict__ hs_out)
{
    const int row = blockIdx.x;
    const int s   = row & (SEQ - 1);
    const int d   = threadIdx.x;

    __shared__ float xs[INDIM];
    __shared__ float w1[4], w2[4];

    if (d < INDIM) xs[d] = x[(size_t)row * INDIM + d];
    __syncthreads();

    const float4* wrow = (const float4*)(enc_w + (size_t)d * INDIM);
    float dot = 0.f;
#pragma unroll
    for (int i = 0; i < INDIM / 4; ++i) {
        float4 w4 = wrow[i];
        dot += w4.x * xs[i * 4 + 0] + w4.y * xs[i * 4 + 1]
             + w4.z * xs[i * 4 + 2] + w4.w * xs[i * 4 + 3];
    }
    float h = dot + enc_b[d] + wpe[(size_t)s * DM + d];

    // block reduction for mean / mean-of-squares over 256 threads
    float v1 = h, v2 = h * h;
#pragma unroll
    for (int mask = 1; mask < 64; mask <<= 1) {
        v1 += __shfl_xor(v1, mask, 64);
        v2 += __shfl_xor(v2, mask, 64);
    }
    if ((d & 63) == 0) { w1[d >> 6] = v1; w2[d >> 6] = v2; }
    __syncthreads();
    float S1 = w1[0] + w1[1] + w1[2] + w1[3];
    float S2 = w2[0] + w2[1] + w2[2] + w2[3];
    float mu  = S1 * (1.f / DM);
    float var = S2 * (1.f / DM) - mu * mu;
    float rs  = rsqrtf(var + 1e-5f);
    float hn  = (h - mu) * rs * ln_g[d] + ln_b[d];
    hs_out[(size_t)row * DM + d] = hn * 0.0625f;   // fold 1/sqrt(256)
}

// ---------------------------------------------------------------------------
// Kernel 2: fused  logits -> online softmax (+argmax) -> quantize -> decoder.
// Block = 256 threads = 16 groups of 16 lanes. Each block owns RPB=4 token
// rows; group g streams vocab rows v = g, g+16, ... Each lane owns 16 of the
// 256 embedding dims (d = o*64 + q*4 + j), so E-row loads are 4x coalesced
// float4 per lane and both the dot and the prob-weighted accumulation reuse
// the same registers. Online-softmax state (m, l, argmax, acc[16]) per group
// per row; merged across the 16 groups at the end via LDS.
// ---------------------------------------------------------------------------
__global__ __launch_bounds__(256, 2) void fused_softmax_quant_kernel(
    const float* __restrict__ emb, const float* __restrict__ hs,
    const float* __restrict__ dec_w, const float* __restrict__ dec_b,
    float* __restrict__ out, float* __restrict__ amax_out)
{
    const int tid  = threadIdx.x;
    const int g    = tid >> 4;   // group 0..15
    const int q    = tid & 15;   // lane within group
    const int row0 = blockIdx.x * RPB;

    __shared__ __align__(16) float q_lds[RPB][DM];
    __shared__ float sm[16][RPB], sl[16][RPB];
    __shared__ int   sam[16][RPB];
    __shared__ float sLf[RPB];

    for (int i = tid; i < RPB * DM; i += 256) (&q_lds[0][0])[i] = 0.f;

    // hs rows cached in registers: lane q owns d = o*64 + q*4 + j
    float4 hsr[RPB][4];
#pragma unroll
    for (int r = 0; r < RPB; ++r)
#pragma unroll
        for (int o = 0; o < 4; ++o)
            hsr[r][o] = *(const float4*)(hs + (size_t)(row0 + r) * DM + o * 64 + q * 4);

    float m[RPB], l[RPB];
    int   am[RPB];
    float4 acc[RPB][4];
#pragma unroll
    for (int r = 0; r < RPB; ++r) {
        m[r] = -INFINITY; l[r] = 0.f; am[r] = 0;
#pragma unroll
        for (int o = 0; o < 4; ++o) acc[r][o] = make_float4(0.f, 0.f, 0.f, 0.f);
    }

    // software prefetch one vocab row ahead (hides ~200cyc L2 latency)
    float ecur[16], enxt[16];
    {
        size_t b0 = (size_t)g * DM + q * 4;
#pragma unroll
        for (int o = 0; o < 4; ++o)
            *(float4*)(enxt + o * 4) = *(const float4*)(emb + b0 + o * 64);
    }

#pragma unroll 1
    for (int v = g; v < VOCAB; v += 16) {
#pragma unroll
        for (int j = 0; j < 16; ++j) ecur[j] = enxt[j];

        int vn = (v + 16 < VOCAB) ? v + 16 : v;     // clamped prefetch
        size_t bn = (size_t)vn * DM + q * 4;
#pragma unroll
        for (int o = 0; o < 4; ++o)
            *(float4*)(enxt + o * 4) = *(const float4*)(emb + bn + o * 64);

        // partial dots, then reduce across the 16 lanes of the group
        float part[RPB];
#pragma unroll
        for (int r = 0; r < RPB; ++r) {
            const float* hp = (const float*)&hsr[r][0];
            float t = 0.f;
#pragma unroll
            for (int j = 0; j < 16; ++j) t += ecur[j] * hp[j];
            part[r] = t;
        }
#pragma unroll
        for (int mask = 8; mask >= 1; mask >>= 1)
#pragma unroll
            for (int r = 0; r < RPB; ++r)
                part[r] += __shfl_xor(part[r], mask, 16);

        // online softmax update (group-uniform branch; rescale is rare)
#pragma unroll
        for (int r = 0; r < RPB; ++r) {
            float lg = part[r];
            float* ap = (float*)&acc[r][0];
            if (lg > m[r]) {
                float c = __expf(m[r] - lg);   // exp(-inf)=0 handles first iter
                m[r] = lg; am[r] = v;
                l[r] = l[r] * c + 1.f;
#pragma unroll
                for (int j = 0; j < 16; ++j) ap[j] = ap[j] * c + ecur[j];
            } else {
                float p = __expf(lg - m[r]);
                l[r] += p;
#pragma unroll
                for (int j = 0; j < 16; ++j) ap[j] += p * ecur[j];
            }
        }
    }

    // ---- merge the 16 groups' softmax states ----
    if (q == 0) {
#pragma unroll
        for (int r = 0; r < RPB; ++r) { sm[g][r] = m[r]; sl[g][r] = l[r]; sam[g][r] = am[r]; }
    }
    __syncthreads();

    float wgt[RPB], Lr[RPB];
    int   A[RPB];
#pragma unroll
    for (int r = 0; r < RPB; ++r) {
        float M = -INFINITY; int a = 0;
        for (int gg = 0; gg < 16; ++gg) {
            float mv = sm[gg][r];
            if (mv > M) { M = mv; a = sam[gg][r]; }
        }
        float L = 0.f;
        for (int gg = 0; gg < 16; ++gg) L += sl[gg][r] * __expf(sm[gg][r] - M);
        wgt[r] = __expf(m[r] - M);
        Lr[r] = L; A[r] = a;
    }

    // scale own acc by group weight, reduce the 4 groups within each wave via
    // shfl (lanes differ only in bits 4-5), then 4-way LDS atomics across waves
#pragma unroll
    for (int r = 0; r < RPB; ++r) {
        const float* ap = (const float*)&acc[r][0];
#pragma unroll
        for (int j = 0; j < 16; ++j) {
            float vs = ap[j] * wgt[r];
            vs += __shfl_xor(vs, 16, 64);
            vs += __shfl_xor(vs, 32, 64);
            if ((g & 3) == 0) {
                int o = j >> 2, c = j & 3;
                atomicAdd(&q_lds[r][o * 64 + q * 4 + c], vs);
            }
        }
    }
    if (tid == 0) {
#pragma unroll
        for (int r = 0; r < RPB; ++r) {
            sLf[r] = Lr[r];
            amax_out[row0 + r] = (float)A[r];   // whole out buffer is read as f32
        }
    }
    __syncthreads();

    // ---- fused decoder: out[r][o] = (sum_d q[d]*dec_w[o,d]) / L + dec_b[o] ----
    {
        const int r = tid >> 6, o = tid & 63;
        const float4* dwp = (const float4*)(dec_w + (size_t)o * DM);
        const float4* qp  = (const float4*)&q_lds[r][0];
        float s = 0.f;
#pragma unroll 8
        for (int d4 = 0; d4 < DM / 4; ++d4) {
            float4 wv = dwp[d4];
            float4 qv = qp[d4];
            s += wv.x * qv.x + wv.y * qv.y + wv.z * qv.z + wv.w * qv.w;
        }
        s = s / sLf[r] + dec_b[o];
        out[(size_t)(row0 + r) * OUTDIM + o] = s;
    }
}

extern "C" void kernel_launch(void* const* d_in, const int* in_sizes, int n_in,
                              void* d_out, int out_size, void* d_ws, size_t ws_size,
                              hipStream_t stream)
{
    const float* x     = (const float*)d_in[0];
    const float* emb   = (const float*)d_in[1];
    const float* wpe   = (const float*)d_in[2];
    const float* enc_w = (const float*)d_in[3];
    const float* enc_b = (const float*)d_in[4];
    const float* ln_g  = (const float*)d_in[5];
    const float* ln_b  = (const float*)d_in[6];
    const float* dec_w = (const float*)d_in[7];
    const float* dec_b = (const float*)d_in[8];

    float* out      = (float*)d_out;
    float* amax_out = out + (size_t)NROWS * OUTDIM;  // second tuple output
    float* hs       = (float*)d_ws;                  // 4096*256 f32 = 4 MB

    encode_ln_kernel<<<NROWS, 256, 0, stream>>>(x, enc_w, enc_b, wpe, ln_g, ln_b, hs);
    fused_softmax_quant_kernel<<<NROWS / RPB, 256, 0, stream>>>(emb, hs, dec_w, dec_b,
                                                                out, amax_out);
}

// Round 2
// 2291.979 us; speedup vs baseline: 2.3008x; 2.3008x over previous
//
#include <hip/hip_runtime.h>
#include <math.h>

#define VOCAB   50257
#define VP      50272      // vocab padded to 32*1571
#define NVT     1571       // vocab tiles of 32 rows
#define DM      256
#define INDIM   64
#define OUTDIM  64
#define NROWS   4096
#define SEQ     1024
#define NSLICE  8
#define NTT     256        // token tiles of 16 rows
#define MARGIN  5e-3f      // argmax safety margin (~15 sigma of fp16-MFMA logit err)
#define FLAGCAP 1024

typedef _Float16 f16;
typedef _Float16 half8 __attribute__((ext_vector_type(8)));
typedef _Float16 half4v __attribute__((ext_vector_type(4)));
typedef float floatx4 __attribute__((ext_vector_type(4)));

// ---------------------------------------------------------------------------
// Kernel 1: encoder GEMM + posemb + LayerNorm. Emits hs (fp32, /16 folded),
// q_hi (fp16 copy for MFMA), and zeroes the flag counter.
// ---------------------------------------------------------------------------
__global__ __launch_bounds__(256) void encode_ln_kernel(
    const float* __restrict__ x, const float* __restrict__ enc_w,
    const float* __restrict__ enc_b, const float* __restrict__ wpe,
    const float* __restrict__ ln_g, const float* __restrict__ ln_b,
    float* __restrict__ hs_out, f16* __restrict__ q_hi, int* flagcnt,
    int write_q)
{
    const int row = blockIdx.x;
    const int s   = row & (SEQ - 1);
    const int d   = threadIdx.x;

    __shared__ float xs[INDIM];
    __shared__ float w1[4], w2[4];

    if (d < INDIM) xs[d] = x[(size_t)row * INDIM + d];
    __syncthreads();

    const float4* wrow = (const float4*)(enc_w + (size_t)d * INDIM);
    float dot = 0.f;
#pragma unroll
    for (int i = 0; i < INDIM / 4; ++i) {
        float4 w4 = wrow[i];
        dot += w4.x * xs[i * 4 + 0] + w4.y * xs[i * 4 + 1]
             + w4.z * xs[i * 4 + 2] + w4.w * xs[i * 4 + 3];
    }
    float h = dot + enc_b[d] + wpe[(size_t)s * DM + d];

    float v1 = h, v2 = h * h;
#pragma unroll
    for (int mask = 1; mask < 64; mask <<= 1) {
        v1 += __shfl_xor(v1, mask, 64);
        v2 += __shfl_xor(v2, mask, 64);
    }
    if ((d & 63) == 0) { w1[d >> 6] = v1; w2[d >> 6] = v2; }
    __syncthreads();
    float S1 = w1[0] + w1[1] + w1[2] + w1[3];
    float S2 = w2[0] + w2[1] + w2[2] + w2[3];
    float mu  = S1 * (1.f / DM);
    float var = S2 * (1.f / DM) - mu * mu;
    float rs  = rsqrtf(var + 1e-5f);
    float hn  = (h - mu) * rs * ln_g[d] + ln_b[d];
    float hsv = hn * 0.0625f;                 // fold 1/sqrt(256)
    hs_out[(size_t)row * DM + d] = hsv;
    if (write_q) q_hi[(size_t)row * DM + d] = (f16)hsv;
    if (row == 0 && d == 0 && write_q) *flagcnt = 0;
}

// ---------------------------------------------------------------------------
// Kernel 2: E (fp32) -> E_hi (fp16 row-major, padded) + E_T (fp16 transposed).
// One block per 32 vocab rows; LDS-tiled transpose, 16B stores.
// ---------------------------------------------------------------------------
__global__ __launch_bounds__(256) void prep_emb(
    const float* __restrict__ emb, f16* __restrict__ e_hi, f16* __restrict__ e_t)
{
    const int v0 = blockIdx.x * 32;
    __shared__ f16 tile[32][DM + 8];
    const int d = threadIdx.x;
    for (int r = 0; r < 32; ++r) {
        int v = v0 + r;
        float val = (v < VOCAB) ? emb[(size_t)v * DM + d] : 0.f;
        f16 h = (f16)val;
        e_hi[(size_t)(v0 + r) * DM + d] = h;
        tile[r][d] = h;
    }
    __syncthreads();
    f16* dst = e_t + (size_t)d * VP + v0;
#pragma unroll
    for (int c = 0; c < 4; ++c) {
        half8 w;
#pragma unroll
        for (int j = 0; j < 8; ++j) w[j] = tile[c * 8 + j][d];
        *(half8*)(dst + c * 8) = w;
    }
}

// ---------------------------------------------------------------------------
// Kernel 3: the fused flash-style MFMA kernel. 1 wave per block, M=16 tokens,
// vocab sliced 8 ways (bid = tt*8+slice => XCD k runs slice k: co-XCD blocks
// sweep identical E tiles => L2 broadcast). Per 32-vocab tile:
//   S^T = E_hi . Q^T  (16x16x32 f16 MFMA, C-layout: v=quad*4+reg, m=lane&15)
//   online softmax (+top-2 +argmax per token column) in registers
//   P -> LDS (per-wave private, no barrier) -> A-frag; O += P . E_T (16 MFMAs)
// ---------------------------------------------------------------------------
__global__ __launch_bounds__(64, 2) void fused_main(
    const f16* __restrict__ e_hi, const f16* __restrict__ e_t,
    const f16* __restrict__ q_hi,
    float* __restrict__ pO, float* __restrict__ pm1, float* __restrict__ pm2,
    float* __restrict__ pl, int* __restrict__ pi1)
{
    const int lane = threadIdx.x;
    const int m_   = lane & 15;
    const int quad = lane >> 4;
    const int slice = blockIdx.x & 7;
    const int tt    = blockIdx.x >> 3;

    __shared__ f16 plds[16][40];   // 16 tokens x 32 v (+8 pad), 16B-aligned rows

    // Q fragments: B[k=d][n=token]: lane holds Q[m=lane&15][d=quad*8+j+32*s]
    half8 qf[8];
    const f16* qb = q_hi + ((size_t)(tt * 16 + m_)) * DM + quad * 8;
#pragma unroll
    for (int s = 0; s < 8; ++s) qf[s] = *(const half8*)(qb + s * 32);

    floatx4 O[16];
#pragma unroll
    for (int i = 0; i < 16; ++i) { O[i][0] = 0.f; O[i][1] = 0.f; O[i][2] = 0.f; O[i][3] = 0.f; }
    float m1 = -INFINITY, m2 = -INFINITY, l = 0.f;
    int i1 = 0;

    const int ntile = (NVT - slice + NSLICE - 1) / NSLICE;
    for (int it = 0; it < ntile; ++it) {
        const int t  = slice + it * NSLICE;
        const int v0 = t * 32;

        // ---- GEMM1: S^T[v][m], two 16-v subtiles ----
        floatx4 sf0, sf1;
        sf0[0]=0.f; sf0[1]=0.f; sf0[2]=0.f; sf0[3]=0.f;
        sf1[0]=0.f; sf1[1]=0.f; sf1[2]=0.f; sf1[3]=0.f;
        const f16* e0 = e_hi + (size_t)(v0 + m_) * DM + quad * 8;
        const f16* e1 = e0 + 16 * DM;
#pragma unroll
        for (int s = 0; s < 8; ++s) {
            half8 a0 = *(const half8*)(e0 + s * 32);
            half8 a1 = *(const half8*)(e1 + s * 32);
            sf0 = __builtin_amdgcn_mfma_f32_16x16x32_f16(a0, qf[s], sf0, 0, 0, 0);
            sf1 = __builtin_amdgcn_mfma_f32_16x16x32_f16(a1, qf[s], sf1, 0, 0, 0);
        }
        // mask padded vocab rows (only the last tile, slice 2)
        if (v0 + 32 > VOCAB) {
#pragma unroll
            for (int r = 0; r < 4; ++r) {
                if (v0 + quad * 4 + r >= VOCAB)      sf0[r] = -INFINITY;
                if (v0 + 16 + quad * 4 + r >= VOCAB) sf1[r] = -INFINITY;
            }
        }

        // ---- tile top-2 (+argmax) per token column ----
        float t1 = -INFINITY, t2 = -INFINITY; int ti = 0;
#pragma unroll
        for (int r = 0; r < 4; ++r) {
            float sv = sf0[r]; int vg = v0 + quad * 4 + r;
            t2 = fmaxf(t2, fminf(t1, sv));
            ti = (sv > t1) ? vg : ti;
            t1 = fmaxf(t1, sv);
        }
#pragma unroll
        for (int r = 0; r < 4; ++r) {
            float sv = sf1[r]; int vg = v0 + 16 + quad * 4 + r;
            t2 = fmaxf(t2, fminf(t1, sv));
            ti = (sv > t1) ? vg : ti;
            t1 = fmaxf(t1, sv);
        }
#pragma unroll
        for (int off = 16; off <= 32; off += 16) {
            float o1 = __shfl_xor(t1, off);
            float o2 = __shfl_xor(t2, off);
            int   oi = __shfl_xor(ti, off);
            t2 = fmaxf(fmaxf(t2, o2), fminf(t1, o1));
            ti = (o1 > t1) ? oi : ti;
            t1 = fmaxf(t1, o1);
        }

        // ---- online softmax update ----
        float m1n = fmaxf(m1, t1);
        bool upd = (t1 > m1);
        m2 = fmaxf(fmaxf(m2, t2), fminf(m1, t1));
        i1 = upd ? ti : i1;
        if (__any(upd)) {
            float c = __expf(m1 - m1n);
            l *= c;
            float co[4];
#pragma unroll
            for (int r = 0; r < 4; ++r) co[r] = __shfl(c, (quad << 2) + r);
#pragma unroll
            for (int nt = 0; nt < 16; ++nt)
#pragma unroll
                for (int r = 0; r < 4; ++r) O[nt][r] *= co[r];
        }
        m1 = m1n;

        float p0[4], p1[4]; float ls = 0.f;
#pragma unroll
        for (int r = 0; r < 4; ++r) { float e = __expf(sf0[r] - m1n); p0[r] = e; ls += e; }
#pragma unroll
        for (int r = 0; r < 4; ++r) { float e = __expf(sf1[r] - m1n); p1[r] = e; ls += e; }
        ls += __shfl_xor(ls, 16);
        ls += __shfl_xor(ls, 32);
        l += ls;

        // ---- P -> LDS (per-wave private), read back as A-fragment ----
        {
            half4v h0, h1;
#pragma unroll
            for (int r = 0; r < 4; ++r) { h0[r] = (f16)p0[r]; h1[r] = (f16)p1[r]; }
            *(half4v*)(&plds[m_][quad * 4])      = h0;
            *(half4v*)(&plds[m_][16 + quad * 4]) = h1;
        }
        __asm__ volatile("s_waitcnt lgkmcnt(0)" ::: "memory");
        half8 a2 = *(const half8*)(&plds[m_][quad * 8]);

        // ---- GEMM2: O[token][d] += P . E (E_T fragments from global) ----
        const f16* eb = e_t + (size_t)m_ * VP + v0 + quad * 8;
#pragma unroll
        for (int nt = 0; nt < 16; ++nt) {
            half8 b2 = *(const half8*)(eb + (size_t)(nt * 16) * VP);
            O[nt] = __builtin_amdgcn_mfma_f32_16x16x32_f16(a2, b2, O[nt], 0, 0, 0);
        }
    }

    // ---- write per-slice partials ----
    const int pid = tt * NSLICE + slice;
    float* ob = pO + (size_t)pid * 16 * DM;
#pragma unroll
    for (int nt = 0; nt < 16; ++nt)
#pragma unroll
        for (int r = 0; r < 4; ++r)
            ob[(quad * 4 + r) * DM + nt * 16 + m_] = O[nt][r];
    if (lane < 16) {
        pm1[pid * 16 + lane] = m1;
        pm2[pid * 16 + lane] = m2;
        pl [pid * 16 + lane] = l;
        pi1[pid * 16 + lane] = i1;
    }
}

// ---------------------------------------------------------------------------
// Kernel 4: merge the 8 slices, emit approximate argmax + margin flags,
// normalize quantize vector, fused decoder.
// ---------------------------------------------------------------------------
__global__ __launch_bounds__(256) void merge_decode(
    const float* __restrict__ pO, const float* __restrict__ pm1,
    const float* __restrict__ pm2, const float* __restrict__ pl,
    const int* __restrict__ pi1,
    const float* __restrict__ dec_w, const float* __restrict__ dec_b,
    float* __restrict__ out, float* __restrict__ amax_out,
    unsigned long long* __restrict__ amax64, int* flagcnt, int* flaglist,
    int* __restrict__ flbyte)
{
    const int tt  = blockIdx.x;
    const int tid = threadIdx.x;
    __shared__ float q_s[16][DM];
    __shared__ float sc[NSLICE][16];
    __shared__ float lI[16];

    if (tid < 16) {
        const int m = tid;
        float M = -INFINITY, M2 = -INFINITY; int win = 0;
        for (int s = 0; s < NSLICE; ++s) {
            float v = pm1[(tt * NSLICE + s) * 16 + m];
            if (v > M) { M2 = M; M = v; win = s; }
            else M2 = fmaxf(M2, v);
        }
        for (int s = 0; s < NSLICE; ++s)
            M2 = fmaxf(M2, pm2[(tt * NSLICE + s) * 16 + m]);
        const int row = tt * 16 + m;
        amax_out[row] = (float)pi1[(tt * NSLICE + win) * 16 + m];
        amax64[row] = 0ull;
        int fl = (M - M2) < MARGIN;
        flbyte[row] = fl;
        if (fl) {
            int pos = atomicAdd(flagcnt, 1);
            if (pos < FLAGCAP) flaglist[pos] = row;
        }
        float lt = 0.f;
        for (int s = 0; s < NSLICE; ++s) {
            float e = __expf(pm1[(tt * NSLICE + s) * 16 + m] - M);
            sc[s][m] = e;
            lt += pl[(tt * NSLICE + s) * 16 + m] * e;
        }
        lI[m] = 1.f / lt;
    }
    __syncthreads();
    {
        const int m = tid >> 4, d0 = (tid & 15) * 16;
        for (int d = d0; d < d0 + 16; ++d) {
            float a = 0.f;
            for (int s = 0; s < NSLICE; ++s)
                a += pO[((size_t)(tt * NSLICE + s) * 16 + m) * DM + d] * sc[s][m];
            q_s[m][d] = a * lI[m];
        }
    }
    __syncthreads();
    {
        const int o = tid & 63;
        const float4* wp = (const float4*)(dec_w + (size_t)o * DM);
#pragma unroll
        for (int k = 0; k < 4; ++k) {
            const int m = (tid >> 6) + k * 4;
            const float4* qp = (const float4*)&q_s[m][0];
            float acc = 0.f;
            for (int d4 = 0; d4 < DM / 4; ++d4) {
                float4 w = wp[d4], q = qp[d4];
                acc += w.x * q.x + w.y * q.y + w.z * q.z + w.w * q.w;
            }
            out[(size_t)(tt * 16 + m) * OUTDIM + o] = acc + dec_b[o];
        }
    }
}

// ---------------------------------------------------------------------------
// Kernel 5: exact fp32 logit recheck for flagged rows (one E sweep total).
// Each block owns a 197-row vocab chunk; atomicMax on (sortable logit, ~idx).
// ---------------------------------------------------------------------------
__global__ __launch_bounds__(256) void recheck_rows(
    const float* __restrict__ emb, const float* __restrict__ hs,
    const int* __restrict__ flagcnt, const int* __restrict__ flaglist,
    unsigned long long* __restrict__ amax64)
{
    int cnt = *flagcnt;
    if (cnt > FLAGCAP) cnt = FLAGCAP;
    if (cnt == 0) return;
    const int vbase = blockIdx.x * 197;
    const int vnum  = min(197, VOCAB - vbase);
    if (vnum <= 0) return;
    __shared__ float e_s[32][DM];
    const int tid = threadIdx.x;
    for (int c0 = 0; c0 < vnum; c0 += 32) {
        const int n = min(32, vnum - c0);
        __syncthreads();
        for (int r = 0; r < n; ++r)
            e_s[r][tid] = emb[(size_t)(vbase + c0 + r) * DM + tid];
        __syncthreads();
        const int vl = tid >> 3, dpart = (tid & 7) * 32;
        for (int f = 0; f < cnt; ++f) {
            const int row = flaglist[f];
            float acc = 0.f;
            if (vl < n) {
                const float* hp = hs + (size_t)row * DM + dpart;
                const float* ep = &e_s[vl][dpart];
                for (int d = 0; d < 32; ++d) acc += hp[d] * ep[d];
            }
            acc += __shfl_xor(acc, 1);
            acc += __shfl_xor(acc, 2);
            acc += __shfl_xor(acc, 4);
            if ((tid & 7) == 0 && vl < n) {
                unsigned u = __float_as_uint(acc);
                u = (u & 0x80000000u) ? ~u : (u | 0x80000000u);
                unsigned long long key =
                    ((unsigned long long)u << 32) | (unsigned)(~(vbase + c0 + vl));
                atomicMax(&amax64[row], key);
            }
        }
    }
}

__global__ void finalize_amax(const int* __restrict__ flbyte,
                              const unsigned long long* __restrict__ amax64,
                              float* __restrict__ amax_out)
{
    int row = blockIdx.x * 256 + threadIdx.x;
    if (row >= NROWS) return;
    if (flbyte[row]) {
        unsigned long long u = amax64[row];
        if (u) {
            unsigned idx = ~(unsigned)(u & 0xffffffffu);
            amax_out[row] = (float)idx;
        }
    }
}

// ---------------------------------------------------------------------------
// Fallback (round-1 VALU kernel) in case ws_size is too small for the staged
// fp16 copies of E.
// ---------------------------------------------------------------------------
#define RPB 4
__global__ __launch_bounds__(256, 2) void fused_softmax_quant_kernel(
    const float* __restrict__ emb, const float* __restrict__ hs,
    const float* __restrict__ dec_w, const float* __restrict__ dec_b,
    float* __restrict__ out, float* __restrict__ amax_out)
{
    const int tid  = threadIdx.x;
    const int g    = tid >> 4;
    const int q    = tid & 15;
    const int row0 = blockIdx.x * RPB;

    __shared__ __align__(16) float q_lds[RPB][DM];
    __shared__ float sm[16][RPB], sl[16][RPB];
    __shared__ int   sam[16][RPB];
    __shared__ float sLf[RPB];

    for (int i = tid; i < RPB * DM; i += 256) (&q_lds[0][0])[i] = 0.f;

    float4 hsr[RPB][4];
#pragma unroll
    for (int r = 0; r < RPB; ++r)
#pragma unroll
        for (int o = 0; o < 4; ++o)
            hsr[r][o] = *(const float4*)(hs + (size_t)(row0 + r) * DM + o * 64 + q * 4);

    float m[RPB], l[RPB];
    int   am[RPB];
    float4 acc[RPB][4];
#pragma unroll
    for (int r = 0; r < RPB; ++r) {
        m[r] = -INFINITY; l[r] = 0.f; am[r] = 0;
#pragma unroll
        for (int o = 0; o < 4; ++o) acc[r][o] = make_float4(0.f, 0.f, 0.f, 0.f);
    }

    float ecur[16], enxt[16];
    {
        size_t b0 = (size_t)g * DM + q * 4;
#pragma unroll
        for (int o = 0; o < 4; ++o)
            *(float4*)(enxt + o * 4) = *(const float4*)(emb + b0 + o * 64);
    }

#pragma unroll 1
    for (int v = g; v < VOCAB; v += 16) {
#pragma unroll
        for (int j = 0; j < 16; ++j) ecur[j] = enxt[j];
        int vn = (v + 16 < VOCAB) ? v + 16 : v;
        size_t bn = (size_t)vn * DM + q * 4;
#pragma unroll
        for (int o = 0; o < 4; ++o)
            *(float4*)(enxt + o * 4) = *(const float4*)(emb + bn + o * 64);

        float part[RPB];
#pragma unroll
        for (int r = 0; r < RPB; ++r) {
            const float* hp = (const float*)&hsr[r][0];
            float t = 0.f;
#pragma unroll
            for (int j = 0; j < 16; ++j) t += ecur[j] * hp[j];
            part[r] = t;
        }
#pragma unroll
        for (int mask = 8; mask >= 1; mask >>= 1)
#pragma unroll
            for (int r = 0; r < RPB; ++r)
                part[r] += __shfl_xor(part[r], mask, 16);

#pragma unroll
        for (int r = 0; r < RPB; ++r) {
            float lg = part[r];
            float* ap = (float*)&acc[r][0];
            if (lg > m[r]) {
                float c = __expf(m[r] - lg);
                m[r] = lg; am[r] = v;
                l[r] = l[r] * c + 1.f;
#pragma unroll
                for (int j = 0; j < 16; ++j) ap[j] = ap[j] * c + ecur[j];
            } else {
                float p = __expf(lg - m[r]);
                l[r] += p;
#pragma unroll
                for (int j = 0; j < 16; ++j) ap[j] += p * ecur[j];
            }
        }
    }

    if (q == 0) {
#pragma unroll
        for (int r = 0; r < RPB; ++r) { sm[g][r] = m[r]; sl[g][r] = l[r]; sam[g][r] = am[r]; }
    }
    __syncthreads();

    float wgt[RPB], Lr[RPB];
    int   A[RPB];
#pragma unroll
    for (int r = 0; r < RPB; ++r) {
        float M = -INFINITY; int a = 0;
        for (int gg = 0; gg < 16; ++gg) {
            float mv = sm[gg][r];
            if (mv > M) { M = mv; a = sam[gg][r]; }
        }
        float L = 0.f;
        for (int gg = 0; gg < 16; ++gg) L += sl[gg][r] * __expf(sm[gg][r] - M);
        wgt[r] = __expf(m[r] - M);
        Lr[r] = L; A[r] = a;
    }

#pragma unroll
    for (int r = 0; r < RPB; ++r) {
        const float* ap = (const float*)&acc[r][0];
#pragma unroll
        for (int j = 0; j < 16; ++j) {
            float vs = ap[j] * wgt[r];
            vs += __shfl_xor(vs, 16, 64);
            vs += __shfl_xor(vs, 32, 64);
            if ((g & 3) == 0) {
                int o = j >> 2, c = j & 3;
                atomicAdd(&q_lds[r][o * 64 + q * 4 + c], vs);
            }
        }
    }
    if (tid == 0) {
#pragma unroll
        for (int r = 0; r < RPB; ++r) {
            sLf[r] = Lr[r];
            amax_out[row0 + r] = (float)A[r];
        }
    }
    __syncthreads();

    {
        const int r = tid >> 6, o = tid & 63;
        const float4* dwp = (const float4*)(dec_w + (size_t)o * DM);
        const float4* qp  = (const float4*)&q_lds[r][0];
        float s = 0.f;
#pragma unroll 8
        for (int d4 = 0; d4 < DM / 4; ++d4) {
            float4 wv = dwp[d4];
            float4 qv = qp[d4];
            s += wv.x * qv.x + wv.y * qv.y + wv.z * qv.z + wv.w * qv.w;
        }
        s = s / sLf[r] + dec_b[o];
        out[(size_t)(row0 + r) * OUTDIM + o] = s;
    }
}

extern "C" void kernel_launch(void* const* d_in, const int* in_sizes, int n_in,
                              void* d_out, int out_size, void* d_ws, size_t ws_size,
                              hipStream_t stream)
{
    const float* x     = (const float*)d_in[0];
    const float* emb   = (const float*)d_in[1];
    const float* wpe   = (const float*)d_in[2];
    const float* enc_w = (const float*)d_in[3];
    const float* enc_b = (const float*)d_in[4];
    const float* ln_g  = (const float*)d_in[5];
    const float* ln_b  = (const float*)d_in[6];
    const float* dec_w = (const float*)d_in[7];
    const float* dec_b = (const float*)d_in[8];

    float* out      = (float*)d_out;
    float* amax_out = out + (size_t)NROWS * OUTDIM;

    // ws layout
    char* w = (char*)d_ws;
    size_t off = 0;
    float* hs = (float*)(w + off);          off += (size_t)NROWS * DM * 4;       // 4 MB
    f16* q_hi = (f16*)(w + off);            off += (size_t)NROWS * DM * 2;       // 2 MB
    f16* e_hi = (f16*)(w + off);            off += (size_t)VP * DM * 2;          // 25.7 MB
    f16* e_t  = (f16*)(w + off);            off += (size_t)DM * VP * 2;          // 25.7 MB
    float* pO = (float*)(w + off);          off += (size_t)NTT * NSLICE * 16 * DM * 4; // 33.5 MB
    float* pm1 = (float*)(w + off);         off += (size_t)NTT * NSLICE * 16 * 4;
    float* pm2 = (float*)(w + off);         off += (size_t)NTT * NSLICE * 16 * 4;
    float* pl  = (float*)(w + off);         off += (size_t)NTT * NSLICE * 16 * 4;
    int*   pi1 = (int*)(w + off);           off += (size_t)NTT * NSLICE * 16 * 4;
    unsigned long long* amax64 = (unsigned long long*)(w + off); off += (size_t)NROWS * 8;
    int* flagcnt  = (int*)(w + off);        off += 256;
    int* flaglist = (int*)(w + off);        off += FLAGCAP * 4;
    int* flbyte   = (int*)(w + off);        off += (size_t)NROWS * 4;

    const bool full = (ws_size >= off);

    encode_ln_kernel<<<NROWS, 256, 0, stream>>>(x, enc_w, enc_b, wpe, ln_g, ln_b,
                                                hs, q_hi, flagcnt, full ? 1 : 0);
    if (full) {
        prep_emb<<<NVT, 256, 0, stream>>>(emb, e_hi, e_t);
        fused_main<<<NTT * NSLICE, 64, 0, stream>>>(e_hi, e_t, q_hi,
                                                    pO, pm1, pm2, pl, pi1);
        merge_decode<<<NTT, 256, 0, stream>>>(pO, pm1, pm2, pl, pi1, dec_w, dec_b,
                                              out, amax_out, amax64, flagcnt,
                                              flaglist, flbyte);
        recheck_rows<<<256, 256, 0, stream>>>(emb, hs, flagcnt, flaglist, amax64);
        finalize_amax<<<(NROWS + 255) / 256, 256, 0, stream>>>(flbyte, amax64, amax_out);
    } else {
        fused_softmax_quant_kernel<<<NROWS / RPB, 256, 0, stream>>>(emb, hs, dec_w,
                                                                    dec_b, out, amax_out);
    }
}

// Round 3
// 1197.998 us; speedup vs baseline: 4.4018x; 1.9132x over previous
//
#include <hip/hip_runtime.h>
#include <math.h>

#define VOCAB   50257
#define VP      50272      // vocab padded to 32*1571
#define NVT     1571       // vocab tiles of 32 rows
#define DM      256
#define INDIM   64
#define OUTDIM  64
#define NROWS   4096
#define SEQ     1024
#define NSLICE  8
#define NTT     64         // token tiles of 64 rows (fused kernel blocks per slice)
#define MARGIN  5e-3f
#define FLAGCAP 1024
#define EP      264        // ehi LDS pitch (f16): 132 dw -> phase-balanced b128
#define TP      40         // et  LDS pitch (f16): 20 dw  -> phase-balanced b128

typedef _Float16 f16;
typedef _Float16 half8 __attribute__((ext_vector_type(8)));
typedef _Float16 half4v __attribute__((ext_vector_type(4)));
typedef float floatx4 __attribute__((ext_vector_type(4)));

// ---------------------------------------------------------------------------
// Kernel 1: encoder GEMM + posemb + LayerNorm -> hs (fp32, /16 folded) + q_hi
// ---------------------------------------------------------------------------
__global__ __launch_bounds__(256) void encode_ln_kernel(
    const float* __restrict__ x, const float* __restrict__ enc_w,
    const float* __restrict__ enc_b, const float* __restrict__ wpe,
    const float* __restrict__ ln_g, const float* __restrict__ ln_b,
    float* __restrict__ hs_out, f16* __restrict__ q_hi, int* flagcnt,
    int write_q)
{
    const int row = blockIdx.x;
    const int s   = row & (SEQ - 1);
    const int d   = threadIdx.x;

    __shared__ float xs[INDIM];
    __shared__ float w1[4], w2[4];

    if (d < INDIM) xs[d] = x[(size_t)row * INDIM + d];
    __syncthreads();

    const float4* wrow = (const float4*)(enc_w + (size_t)d * INDIM);
    float dot = 0.f;
#pragma unroll
    for (int i = 0; i < INDIM / 4; ++i) {
        float4 w4 = wrow[i];
        dot += w4.x * xs[i * 4 + 0] + w4.y * xs[i * 4 + 1]
             + w4.z * xs[i * 4 + 2] + w4.w * xs[i * 4 + 3];
    }
    float h = dot + enc_b[d] + wpe[(size_t)s * DM + d];

    float v1 = h, v2 = h * h;
#pragma unroll
    for (int mask = 1; mask < 64; mask <<= 1) {
        v1 += __shfl_xor(v1, mask, 64);
        v2 += __shfl_xor(v2, mask, 64);
    }
    if ((d & 63) == 0) { w1[d >> 6] = v1; w2[d >> 6] = v2; }
    __syncthreads();
    float S1 = w1[0] + w1[1] + w1[2] + w1[3];
    float S2 = w2[0] + w2[1] + w2[2] + w2[3];
    float mu  = S1 * (1.f / DM);
    float var = S2 * (1.f / DM) - mu * mu;
    float rs  = rsqrtf(var + 1e-5f);
    float hn  = (h - mu) * rs * ln_g[d] + ln_b[d];
    float hsv = hn * 0.0625f;
    hs_out[(size_t)row * DM + d] = hsv;
    if (write_q) q_hi[(size_t)row * DM + d] = (f16)hsv;
    if (row == 0 && d == 0 && write_q) *flagcnt = 0;
}

// ---------------------------------------------------------------------------
// Kernel 2: E (fp32) -> E_hi (fp16 row-major, VP rows) + E_T (fp16 [d][v]).
// 128-row tiles so transposed stores are 256 B contiguous per d-row.
// ---------------------------------------------------------------------------
__global__ __launch_bounds__(256) void prep_emb(
    const float* __restrict__ emb, f16* __restrict__ e_hi, f16* __restrict__ e_t)
{
    const int v0 = blockIdx.x * 128;
    const int tid = threadIdx.x;
    __shared__ f16 tile[128][EP];

    // phase A: row-major convert + store, fill LDS tile
#pragma unroll 2
    for (int i = 0; i < 16; ++i) {
        int row = i * 8 + (tid >> 5);
        int col = (tid & 31) * 8;
        int v = v0 + row;
        half8 h;
        if (v < VOCAB) {
            const float* src = emb + (size_t)v * DM + col;
            float4 f0 = *(const float4*)(src);
            float4 f1 = *(const float4*)(src + 4);
            h[0]=(f16)f0.x; h[1]=(f16)f0.y; h[2]=(f16)f0.z; h[3]=(f16)f0.w;
            h[4]=(f16)f1.x; h[5]=(f16)f1.y; h[6]=(f16)f1.z; h[7]=(f16)f1.w;
        } else {
#pragma unroll
            for (int j = 0; j < 8; ++j) h[j] = (f16)0.f;
        }
        if (v < VP) *(half8*)(e_hi + (size_t)v * DM + col) = h;
        *(half8*)&tile[row][col] = h;
    }
    __syncthreads();

    // phase B: transposed store, 16 chunks of 8 v per d-row (256 B contiguous)
    const int cc = tid & 15;
    const bool ok = (v0 + cc * 8) < VP;
#pragma unroll 2
    for (int rr = 0; rr < 16; ++rr) {
        int d = rr * 16 + (tid >> 4);
        half8 w;
#pragma unroll
        for (int j = 0; j < 8; ++j) w[j] = tile[cc * 8 + j][d];
        if (ok) *(half8*)(e_t + (size_t)d * VP + v0 + cc * 8) = w;
    }
}

// ---------------------------------------------------------------------------
// Kernel 3: fused flash-style MFMA kernel. Block = 4 waves = 64 tokens;
// vocab sliced 8 ways (bid = tt*8+slice -> XCD k gets slice k). Per 32-vocab
// tile both E layouts are staged once into double-buffered LDS and shared by
// the 4 waves (4x less L2 traffic than per-wave global reads).
// ---------------------------------------------------------------------------
__global__ __launch_bounds__(256, 2) void fused_main(
    const f16* __restrict__ e_hi, const f16* __restrict__ e_t,
    const f16* __restrict__ q_hi,
    float* __restrict__ pO, float* __restrict__ pm1, float* __restrict__ pm2,
    float* __restrict__ pl, int* __restrict__ pi1)
{
    const int tid  = threadIdx.x;
    const int wave = tid >> 6;
    const int lane = tid & 63;
    const int m_   = lane & 15;
    const int quad = lane >> 4;
    const int slice = blockIdx.x & 7;
    const int tt    = blockIdx.x >> 3;

    __shared__ f16 ehi_s[2][32][EP];    // 33.8 KB
    __shared__ f16 et_s[2][DM][TP];     // 41.0 KB
    __shared__ f16 plds[4][16][40];     // 5.1 KB (per-wave private)

    // Q fragments (B-operand): lane holds Q[tok=m_][d=quad*8+j+32*s]
    half8 qf[8];
    const f16* qb = q_hi + ((size_t)(tt * 64 + wave * 16 + m_)) * DM + quad * 8;
#pragma unroll
    for (int s = 0; s < 8; ++s) qf[s] = *(const half8*)(qb + s * 32);

    floatx4 O[16];
#pragma unroll
    for (int i = 0; i < 16; ++i) { O[i][0]=0.f; O[i][1]=0.f; O[i][2]=0.f; O[i][3]=0.f; }
    float m1 = -INFINITY, m2 = -INFINITY, l = 0.f;
    int i1 = 0;

    const int ntile = (NVT - slice + NSLICE - 1) / NSLICE;

    // staging registers
    half8 rA[4], rB[4];
    const int sr2 = lane >> 5, sc = lane & 31;     // e_hi map: 2 rows x 32 chunks
    const int dr = lane >> 2, vc = lane & 3;       // e_t map: 16 d-rows x 4 chunks

    // prologue: stage tile 0 into buf 0
    {
        const int v0 = slice * 32;
#pragma unroll
        for (int i = 0; i < 4; ++i) {
            int row = wave * 8 + i * 2 + sr2;
            rA[i] = *(const half8*)(e_hi + (size_t)(v0 + row) * DM + sc * 8);
        }
#pragma unroll
        for (int i = 0; i < 4; ++i) {
            int d = wave * 64 + i * 16 + dr;
            rB[i] = *(const half8*)(e_t + (size_t)d * VP + v0 + vc * 8);
        }
#pragma unroll
        for (int i = 0; i < 4; ++i) {
            int row = wave * 8 + i * 2 + sr2;
            *(half8*)&ehi_s[0][row][sc * 8] = rA[i];
        }
#pragma unroll
        for (int i = 0; i < 4; ++i) {
            int d = wave * 64 + i * 16 + dr;
            *(half8*)&et_s[0][d][vc * 8] = rB[i];
        }
    }
    __syncthreads();

    for (int it = 0; it < ntile; ++it) {
        const int b  = it & 1;
        const int v0 = (slice + it * NSLICE) * 32;
        const bool pre = (it + 1 < ntile);

        if (pre) {
            const int vn = v0 + NSLICE * 32;
#pragma unroll
            for (int i = 0; i < 4; ++i) {
                int row = wave * 8 + i * 2 + sr2;
                rA[i] = *(const half8*)(e_hi + (size_t)(vn + row) * DM + sc * 8);
            }
#pragma unroll
            for (int i = 0; i < 4; ++i) {
                int d = wave * 64 + i * 16 + dr;
                rB[i] = *(const half8*)(e_t + (size_t)d * VP + vn + vc * 8);
            }
        }

        // ---- GEMM1: S^T[v][tok] from LDS ----
        floatx4 sf0, sf1;
        sf0[0]=0.f; sf0[1]=0.f; sf0[2]=0.f; sf0[3]=0.f;
        sf1[0]=0.f; sf1[1]=0.f; sf1[2]=0.f; sf1[3]=0.f;
#pragma unroll
        for (int s = 0; s < 8; ++s) {
            half8 a0 = *(const half8*)&ehi_s[b][m_][s * 32 + quad * 8];
            half8 a1 = *(const half8*)&ehi_s[b][m_ + 16][s * 32 + quad * 8];
            sf0 = __builtin_amdgcn_mfma_f32_16x16x32_f16(a0, qf[s], sf0, 0, 0, 0);
            sf1 = __builtin_amdgcn_mfma_f32_16x16x32_f16(a1, qf[s], sf1, 0, 0, 0);
        }
        if (v0 + 32 > VOCAB) {
#pragma unroll
            for (int r = 0; r < 4; ++r) {
                if (v0 + quad * 4 + r >= VOCAB)      sf0[r] = -INFINITY;
                if (v0 + 16 + quad * 4 + r >= VOCAB) sf1[r] = -INFINITY;
            }
        }

        // ---- tile top-2 (+argmax) per token column ----
        float t1 = -INFINITY, t2 = -INFINITY; int ti = 0;
#pragma unroll
        for (int r = 0; r < 4; ++r) {
            float sv = sf0[r]; int vg = v0 + quad * 4 + r;
            t2 = fmaxf(t2, fminf(t1, sv));
            ti = (sv > t1) ? vg : ti;
            t1 = fmaxf(t1, sv);
        }
#pragma unroll
        for (int r = 0; r < 4; ++r) {
            float sv = sf1[r]; int vg = v0 + 16 + quad * 4 + r;
            t2 = fmaxf(t2, fminf(t1, sv));
            ti = (sv > t1) ? vg : ti;
            t1 = fmaxf(t1, sv);
        }
#pragma unroll
        for (int off = 16; off <= 32; off += 16) {
            float o1 = __shfl_xor(t1, off);
            float o2 = __shfl_xor(t2, off);
            int   oi = __shfl_xor(ti, off);
            t2 = fmaxf(fmaxf(t2, o2), fminf(t1, o1));
            ti = (o1 > t1) ? oi : ti;
            t1 = fmaxf(t1, o1);
        }

        // ---- online softmax update ----
        float m1n = fmaxf(m1, t1);
        bool upd = (t1 > m1);
        m2 = fmaxf(fmaxf(m2, t2), fminf(m1, t1));
        i1 = upd ? ti : i1;
        if (__any(upd)) {
            float c = __expf(m1 - m1n);
            l *= c;
            float co[4];
#pragma unroll
            for (int r = 0; r < 4; ++r) co[r] = __shfl(c, (quad << 2) + r);
#pragma unroll
            for (int nt = 0; nt < 16; ++nt)
#pragma unroll
                for (int r = 0; r < 4; ++r) O[nt][r] *= co[r];
        }
        m1 = m1n;

        float p0[4], p1[4]; float ls = 0.f;
#pragma unroll
        for (int r = 0; r < 4; ++r) { float e = __expf(sf0[r] - m1n); p0[r] = e; ls += e; }
#pragma unroll
        for (int r = 0; r < 4; ++r) { float e = __expf(sf1[r] - m1n); p1[r] = e; ls += e; }
        ls += __shfl_xor(ls, 16);
        ls += __shfl_xor(ls, 32);
        l += ls;

        // ---- P -> private LDS -> A-fragment ----
        {
            half4v h0, h1;
#pragma unroll
            for (int r = 0; r < 4; ++r) { h0[r] = (f16)p0[r]; h1[r] = (f16)p1[r]; }
            *(half4v*)(&plds[wave][m_][quad * 4])      = h0;
            *(half4v*)(&plds[wave][m_][16 + quad * 4]) = h1;
        }
        __asm__ volatile("s_waitcnt lgkmcnt(0)" ::: "memory");
        half8 a2 = *(const half8*)(&plds[wave][m_][quad * 8]);

        // ---- GEMM2: O[tok][d] += P . E from LDS ----
#pragma unroll
        for (int nt = 0; nt < 16; ++nt) {
            half8 b2 = *(const half8*)&et_s[b][nt * 16 + m_][quad * 8];
            O[nt] = __builtin_amdgcn_mfma_f32_16x16x32_f16(a2, b2, O[nt], 0, 0, 0);
        }

        if (pre) {
#pragma unroll
            for (int i = 0; i < 4; ++i) {
                int row = wave * 8 + i * 2 + sr2;
                *(half8*)&ehi_s[b ^ 1][row][sc * 8] = rA[i];
            }
#pragma unroll
            for (int i = 0; i < 4; ++i) {
                int d = wave * 64 + i * 16 + dr;
                *(half8*)&et_s[b ^ 1][d][vc * 8] = rB[i];
            }
        }
        __syncthreads();
    }

    // ---- write per-slice partials ----
    const int trow0 = tt * 64 + wave * 16;
    float* ob = pO + ((size_t)slice * NROWS + trow0) * DM;
#pragma unroll
    for (int nt = 0; nt < 16; ++nt)
#pragma unroll
        for (int r = 0; r < 4; ++r)
            ob[(size_t)(quad * 4 + r) * DM + nt * 16 + m_] = O[nt][r];
    if (lane < 16) {
        const int idx = slice * NROWS + trow0 + lane;
        pm1[idx] = m1;
        pm2[idx] = m2;
        pl [idx] = l;
        pi1[idx] = i1;
    }
}

// ---------------------------------------------------------------------------
// Kernel 4: merge slices, approximate argmax + margin flags, decoder.
// ---------------------------------------------------------------------------
__global__ __launch_bounds__(256) void merge_decode(
    const float* __restrict__ pO, const float* __restrict__ pm1,
    const float* __restrict__ pm2, const float* __restrict__ pl,
    const int* __restrict__ pi1,
    const float* __restrict__ dec_w, const float* __restrict__ dec_b,
    float* __restrict__ out, float* __restrict__ amax_out,
    unsigned long long* __restrict__ amax64, int* flagcnt, int* flaglist,
    int* __restrict__ flbyte)
{
    const int tt  = blockIdx.x;         // 16-token tiles
    const int tid = threadIdx.x;
    __shared__ float q_s[16][DM];
    __shared__ float sc[NSLICE][16];
    __shared__ float lI[16];

    if (tid < 16) {
        const int row = tt * 16 + tid;
        float M = -INFINITY, M2 = -INFINITY; int win = 0;
        for (int s = 0; s < NSLICE; ++s) {
            float v = pm1[s * NROWS + row];
            if (v > M) { M2 = M; M = v; win = s; }
            else M2 = fmaxf(M2, v);
        }
        for (int s = 0; s < NSLICE; ++s)
            M2 = fmaxf(M2, pm2[s * NROWS + row]);
        amax_out[row] = (float)pi1[win * NROWS + row];
        amax64[row] = 0ull;
        int fl = (M - M2) < MARGIN;
        flbyte[row] = fl;
        if (fl) {
            int pos = atomicAdd(flagcnt, 1);
            if (pos < FLAGCAP) flaglist[pos] = row;
        }
        float lt = 0.f;
        for (int s = 0; s < NSLICE; ++s) {
            float e = __expf(pm1[s * NROWS + row] - M);
            sc[s][tid] = e;
            lt += pl[s * NROWS + row] * e;
        }
        lI[tid] = 1.f / lt;
    }
    __syncthreads();
    {
        const int m = tid >> 4, d0 = (tid & 15) * 16;
        const int row = tt * 16 + m;
        for (int d = d0; d < d0 + 16; ++d) {
            float a = 0.f;
            for (int s = 0; s < NSLICE; ++s)
                a += pO[((size_t)s * NROWS + row) * DM + d] * sc[s][m];
            q_s[m][d] = a * lI[m];
        }
    }
    __syncthreads();
    {
        const int o = tid & 63;
        const float4* wp = (const float4*)(dec_w + (size_t)o * DM);
#pragma unroll
        for (int k = 0; k < 4; ++k) {
            const int m = (tid >> 6) + k * 4;
            const float4* qp = (const float4*)&q_s[m][0];
            float acc = 0.f;
            for (int d4 = 0; d4 < DM / 4; ++d4) {
                float4 w = wp[d4], q = qp[d4];
                acc += w.x * q.x + w.y * q.y + w.z * q.z + w.w * q.w;
            }
            out[(size_t)(tt * 16 + m) * OUTDIM + o] = acc + dec_b[o];
        }
    }
}

// ---------------------------------------------------------------------------
// Kernel 5: exact fp32 recheck of flagged rows (one E sweep total).
// ---------------------------------------------------------------------------
__global__ __launch_bounds__(256) void recheck_rows(
    const float* __restrict__ emb, const float* __restrict__ hs,
    const int* __restrict__ flagcnt, const int* __restrict__ flaglist,
    unsigned long long* __restrict__ amax64)
{
    int cnt = *flagcnt;
    if (cnt > FLAGCAP) cnt = FLAGCAP;
    if (cnt == 0) return;
    const int vbase = blockIdx.x * 197;
    const int vnum  = min(197, VOCAB - vbase);
    if (vnum <= 0) return;
    __shared__ float e_s[32][DM];
    const int tid = threadIdx.x;
    for (int c0 = 0; c0 < vnum; c0 += 32) {
        const int n = min(32, vnum - c0);
        __syncthreads();
        for (int r = 0; r < n; ++r)
            e_s[r][tid] = emb[(size_t)(vbase + c0 + r) * DM + tid];
        __syncthreads();
        const int vl = tid >> 3, dpart = (tid & 7) * 32;
        for (int f = 0; f < cnt; ++f) {
            const int row = flaglist[f];
            float acc = 0.f;
            if (vl < n) {
                const float* hp = hs + (size_t)row * DM + dpart;
                const float* ep = &e_s[vl][dpart];
                for (int d = 0; d < 32; ++d) acc += hp[d] * ep[d];
            }
            acc += __shfl_xor(acc, 1);
            acc += __shfl_xor(acc, 2);
            acc += __shfl_xor(acc, 4);
            if ((tid & 7) == 0 && vl < n) {
                unsigned u = __float_as_uint(acc);
                u = (u & 0x80000000u) ? ~u : (u | 0x80000000u);
                unsigned long long key =
                    ((unsigned long long)u << 32) | (unsigned)(~(vbase + c0 + vl));
                atomicMax(&amax64[row], key);
            }
        }
    }
}

__global__ void finalize_amax(const int* __restrict__ flbyte,
                              const unsigned long long* __restrict__ amax64,
                              float* __restrict__ amax_out)
{
    int row = blockIdx.x * 256 + threadIdx.x;
    if (row >= NROWS) return;
    if (flbyte[row]) {
        unsigned long long u = amax64[row];
        if (u) {
            unsigned idx = ~(unsigned)(u & 0xffffffffu);
            amax_out[row] = (float)idx;
        }
    }
}

// ---------------------------------------------------------------------------
// Fallback (round-1 VALU kernel) if ws_size is too small.
// ---------------------------------------------------------------------------
#define RPB 4
__global__ __launch_bounds__(256, 2) void fused_softmax_quant_kernel(
    const float* __restrict__ emb, const float* __restrict__ hs,
    const float* __restrict__ dec_w, const float* __restrict__ dec_b,
    float* __restrict__ out, float* __restrict__ amax_out)
{
    const int tid  = threadIdx.x;
    const int g    = tid >> 4;
    const int q    = tid & 15;
    const int row0 = blockIdx.x * RPB;

    __shared__ __align__(16) float q_lds[RPB][DM];
    __shared__ float sm[16][RPB], sl[16][RPB];
    __shared__ int   sam[16][RPB];
    __shared__ float sLf[RPB];

    for (int i = tid; i < RPB * DM; i += 256) (&q_lds[0][0])[i] = 0.f;

    float4 hsr[RPB][4];
#pragma unroll
    for (int r = 0; r < RPB; ++r)
#pragma unroll
        for (int o = 0; o < 4; ++o)
            hsr[r][o] = *(const float4*)(hs + (size_t)(row0 + r) * DM + o * 64 + q * 4);

    float m[RPB], l[RPB];
    int   am[RPB];
    float4 acc[RPB][4];
#pragma unroll
    for (int r = 0; r < RPB; ++r) {
        m[r] = -INFINITY; l[r] = 0.f; am[r] = 0;
#pragma unroll
        for (int o = 0; o < 4; ++o) acc[r][o] = make_float4(0.f, 0.f, 0.f, 0.f);
    }

    float ecur[16], enxt[16];
    {
        size_t b0 = (size_t)g * DM + q * 4;
#pragma unroll
        for (int o = 0; o < 4; ++o)
            *(float4*)(enxt + o * 4) = *(const float4*)(emb + b0 + o * 64);
    }

#pragma unroll 1
    for (int v = g; v < VOCAB; v += 16) {
#pragma unroll
        for (int j = 0; j < 16; ++j) ecur[j] = enxt[j];
        int vn = (v + 16 < VOCAB) ? v + 16 : v;
        size_t bn = (size_t)vn * DM + q * 4;
#pragma unroll
        for (int o = 0; o < 4; ++o)
            *(float4*)(enxt + o * 4) = *(const float4*)(emb + bn + o * 64);

        float part[RPB];
#pragma unroll
        for (int r = 0; r < RPB; ++r) {
            const float* hp = (const float*)&hsr[r][0];
            float t = 0.f;
#pragma unroll
            for (int j = 0; j < 16; ++j) t += ecur[j] * hp[j];
            part[r] = t;
        }
#pragma unroll
        for (int mask = 8; mask >= 1; mask >>= 1)
#pragma unroll
            for (int r = 0; r < RPB; ++r)
                part[r] += __shfl_xor(part[r], mask, 16);

#pragma unroll
        for (int r = 0; r < RPB; ++r) {
            float lg = part[r];
            float* ap = (float*)&acc[r][0];
            if (lg > m[r]) {
                float c = __expf(m[r] - lg);
                m[r] = lg; am[r] = v;
                l[r] = l[r] * c + 1.f;
#pragma unroll
                for (int j = 0; j < 16; ++j) ap[j] = ap[j] * c + ecur[j];
            } else {
                float p = __expf(lg - m[r]);
                l[r] += p;
#pragma unroll
                for (int j = 0; j < 16; ++j) ap[j] += p * ecur[j];
            }
        }
    }

    if (q == 0) {
#pragma unroll
        for (int r = 0; r < RPB; ++r) { sm[g][r] = m[r]; sl[g][r] = l[r]; sam[g][r] = am[r]; }
    }
    __syncthreads();

    float wgt[RPB], Lr[RPB];
    int   A[RPB];
#pragma unroll
    for (int r = 0; r < RPB; ++r) {
        float M = -INFINITY; int a = 0;
        for (int gg = 0; gg < 16; ++gg) {
            float mv = sm[gg][r];
            if (mv > M) { M = mv; a = sam[gg][r]; }
        }
        float L = 0.f;
        for (int gg = 0; gg < 16; ++gg) L += sl[gg][r] * __expf(sm[gg][r] - M);
        wgt[r] = __expf(m[r] - M);
        Lr[r] = L; A[r] = a;
    }

#pragma unroll
    for (int r = 0; r < RPB; ++r) {
        const float* ap = (const float*)&acc[r][0];
#pragma unroll
        for (int j = 0; j < 16; ++j) {
            float vs = ap[j] * wgt[r];
            vs += __shfl_xor(vs, 16, 64);
            vs += __shfl_xor(vs, 32, 64);
            if ((g & 3) == 0) {
                int o = j >> 2, c = j & 3;
                atomicAdd(&q_lds[r][o * 64 + q * 4 + c], vs);
            }
        }
    }
    if (tid == 0) {
#pragma unroll
        for (int r = 0; r < RPB; ++r) {
            sLf[r] = Lr[r];
            amax_out[row0 + r] = (float)A[r];
        }
    }
    __syncthreads();

    {
        const int r = tid >> 6, o = tid & 63;
        const float4* dwp = (const float4*)(dec_w + (size_t)o * DM);
        const float4* qp  = (const float4*)&q_lds[r][0];
        float s = 0.f;
#pragma unroll 8
        for (int d4 = 0; d4 < DM / 4; ++d4) {
            float4 wv = dwp[d4];
            float4 qv = qp[d4];
            s += wv.x * qv.x + wv.y * qv.y + wv.z * qv.z + wv.w * qv.w;
        }
        s = s / sLf[r] + dec_b[o];
        out[(size_t)(row0 + r) * OUTDIM + o] = s;
    }
}

extern "C" void kernel_launch(void* const* d_in, const int* in_sizes, int n_in,
                              void* d_out, int out_size, void* d_ws, size_t ws_size,
                              hipStream_t stream)
{
    const float* x     = (const float*)d_in[0];
    const float* emb   = (const float*)d_in[1];
    const float* wpe   = (const float*)d_in[2];
    const float* enc_w = (const float*)d_in[3];
    const float* enc_b = (const float*)d_in[4];
    const float* ln_g  = (const float*)d_in[5];
    const float* ln_b  = (const float*)d_in[6];
    const float* dec_w = (const float*)d_in[7];
    const float* dec_b = (const float*)d_in[8];

    float* out      = (float*)d_out;
    float* amax_out = out + (size_t)NROWS * OUTDIM;

    char* w = (char*)d_ws;
    size_t off = 0;
    float* hs = (float*)(w + off);          off += (size_t)NROWS * DM * 4;
    f16* q_hi = (f16*)(w + off);            off += (size_t)NROWS * DM * 2;
    f16* e_hi = (f16*)(w + off);            off += (size_t)VP * DM * 2;
    f16* e_t  = (f16*)(w + off);            off += (size_t)DM * VP * 2;
    float* pO = (float*)(w + off);          off += (size_t)NSLICE * NROWS * DM * 4;
    float* pm1 = (float*)(w + off);         off += (size_t)NSLICE * NROWS * 4;
    float* pm2 = (float*)(w + off);         off += (size_t)NSLICE * NROWS * 4;
    float* pl  = (float*)(w + off);         off += (size_t)NSLICE * NROWS * 4;
    int*   pi1 = (int*)(w + off);           off += (size_t)NSLICE * NROWS * 4;
    unsigned long long* amax64 = (unsigned long long*)(w + off); off += (size_t)NROWS * 8;
    int* flagcnt  = (int*)(w + off);        off += 256;
    int* flaglist = (int*)(w + off);        off += FLAGCAP * 4;
    int* flbyte   = (int*)(w + off);        off += (size_t)NROWS * 4;

    const bool full = (ws_size >= off);

    encode_ln_kernel<<<NROWS, 256, 0, stream>>>(x, enc_w, enc_b, wpe, ln_g, ln_b,
                                                hs, q_hi, flagcnt, full ? 1 : 0);
    if (full) {
        prep_emb<<<(VP + 127) / 128, 256, 0, stream>>>(emb, e_hi, e_t);
        fused_main<<<NTT * NSLICE, 256, 0, stream>>>(e_hi, e_t, q_hi,
                                                     pO, pm1, pm2, pl, pi1);
        merge_decode<<<NROWS / 16, 256, 0, stream>>>(pO, pm1, pm2, pl, pi1, dec_w, dec_b,
                                                     out, amax_out, amax64, flagcnt,
                                                     flaglist, flbyte);
        recheck_rows<<<256, 256, 0, stream>>>(emb, hs, flagcnt, flaglist, amax64);
        finalize_amax<<<(NROWS + 255) / 256, 256, 0, stream>>>(flbyte, amax64, amax_out);
    } else {
        fused_softmax_quant_kernel<<<NROWS / RPB, 256, 0, stream>>>(emb, hs, dec_w,
                                                                    dec_b, out, amax_out);
    }
}

// Round 4
// 655.453 us; speedup vs baseline: 8.0454x; 1.8277x over previous
//
#include <hip/hip_runtime.h>
#include <math.h>

#define VOCAB   50257
#define VP      50272      // vocab padded to 32*1571
#define NVT     1571       // vocab tiles of 32 rows
#define DM      256
#define INDIM   64
#define OUTDIM  64
#define NROWS   4096
#define SEQ     1024
#define NSLICE  8
#define NTT     64         // token tiles of 64 rows (fused kernel blocks per slice)
#define MARGIN  5e-3f
#define FLAGCAP 1024
#define EP      264        // ehi LDS pitch (f16)
#define TP      40         // et  LDS pitch (f16)

typedef _Float16 f16;
typedef _Float16 half8 __attribute__((ext_vector_type(8)));
typedef _Float16 half4v __attribute__((ext_vector_type(4)));
typedef float floatx4 __attribute__((ext_vector_type(4)));

// ---------------------------------------------------------------------------
// Kernel 1: encoder GEMM + posemb + LayerNorm -> hs (fp32, /16 folded),
// q_hi + q_lo (split fp16 for MFMA paths).
// ---------------------------------------------------------------------------
__global__ __launch_bounds__(256) void encode_ln_kernel(
    const float* __restrict__ x, const float* __restrict__ enc_w,
    const float* __restrict__ enc_b, const float* __restrict__ wpe,
    const float* __restrict__ ln_g, const float* __restrict__ ln_b,
    float* __restrict__ hs_out, f16* __restrict__ q_hi, f16* __restrict__ q_lo,
    int* flagcnt, int write_q)
{
    const int row = blockIdx.x;
    const int s   = row & (SEQ - 1);
    const int d   = threadIdx.x;

    __shared__ float xs[INDIM];
    __shared__ float w1[4], w2[4];

    if (d < INDIM) xs[d] = x[(size_t)row * INDIM + d];
    __syncthreads();

    const float4* wrow = (const float4*)(enc_w + (size_t)d * INDIM);
    float dot = 0.f;
#pragma unroll
    for (int i = 0; i < INDIM / 4; ++i) {
        float4 w4 = wrow[i];
        dot += w4.x * xs[i * 4 + 0] + w4.y * xs[i * 4 + 1]
             + w4.z * xs[i * 4 + 2] + w4.w * xs[i * 4 + 3];
    }
    float h = dot + enc_b[d] + wpe[(size_t)s * DM + d];

    float v1 = h, v2 = h * h;
#pragma unroll
    for (int mask = 1; mask < 64; mask <<= 1) {
        v1 += __shfl_xor(v1, mask, 64);
        v2 += __shfl_xor(v2, mask, 64);
    }
    if ((d & 63) == 0) { w1[d >> 6] = v1; w2[d >> 6] = v2; }
    __syncthreads();
    float S1 = w1[0] + w1[1] + w1[2] + w1[3];
    float S2 = w2[0] + w2[1] + w2[2] + w2[3];
    float mu  = S1 * (1.f / DM);
    float var = S2 * (1.f / DM) - mu * mu;
    float rs  = rsqrtf(var + 1e-5f);
    float hn  = (h - mu) * rs * ln_g[d] + ln_b[d];
    float hsv = hn * 0.0625f;
    hs_out[(size_t)row * DM + d] = hsv;
    if (write_q) {
        f16 hi = (f16)hsv;
        q_hi[(size_t)row * DM + d] = hi;
        q_lo[(size_t)row * DM + d] = (f16)(hsv - (float)hi);
    }
    if (row == 0 && d == 0 && write_q) *flagcnt = 0;
}

// ---------------------------------------------------------------------------
// Kernel 2: E (fp32) -> E_hi (fp16 row-major, VP rows) + E_T (fp16 [d][v]).
// ---------------------------------------------------------------------------
__global__ __launch_bounds__(256) void prep_emb(
    const float* __restrict__ emb, f16* __restrict__ e_hi, f16* __restrict__ e_t)
{
    const int v0 = blockIdx.x * 128;
    const int tid = threadIdx.x;
    __shared__ f16 tile[128][EP];

#pragma unroll 2
    for (int i = 0; i < 16; ++i) {
        int row = i * 8 + (tid >> 5);
        int col = (tid & 31) * 8;
        int v = v0 + row;
        half8 h;
        if (v < VOCAB) {
            const float* src = emb + (size_t)v * DM + col;
            float4 f0 = *(const float4*)(src);
            float4 f1 = *(const float4*)(src + 4);
            h[0]=(f16)f0.x; h[1]=(f16)f0.y; h[2]=(f16)f0.z; h[3]=(f16)f0.w;
            h[4]=(f16)f1.x; h[5]=(f16)f1.y; h[6]=(f16)f1.z; h[7]=(f16)f1.w;
        } else {
#pragma unroll
            for (int j = 0; j < 8; ++j) h[j] = (f16)0.f;
        }
        if (v < VP) *(half8*)(e_hi + (size_t)v * DM + col) = h;
        *(half8*)&tile[row][col] = h;
    }
    __syncthreads();

    const int cc = tid & 15;
    const bool ok = (v0 + cc * 8) < VP;
#pragma unroll 2
    for (int rr = 0; rr < 16; ++rr) {
        int d = rr * 16 + (tid >> 4);
        half8 w;
#pragma unroll
        for (int j = 0; j < 8; ++j) w[j] = tile[cc * 8 + j][d];
        if (ok) *(half8*)(e_t + (size_t)d * VP + v0 + cc * 8) = w;
    }
}

// ---------------------------------------------------------------------------
// Kernel 3: fused flash-style MFMA kernel (unchanged from round 3).
// ---------------------------------------------------------------------------
__global__ __launch_bounds__(256, 2) void fused_main(
    const f16* __restrict__ e_hi, const f16* __restrict__ e_t,
    const f16* __restrict__ q_hi,
    float* __restrict__ pO, float* __restrict__ pm1, float* __restrict__ pm2,
    float* __restrict__ pl, int* __restrict__ pi1)
{
    const int tid  = threadIdx.x;
    const int wave = tid >> 6;
    const int lane = tid & 63;
    const int m_   = lane & 15;
    const int quad = lane >> 4;
    const int slice = blockIdx.x & 7;
    const int tt    = blockIdx.x >> 3;

    __shared__ f16 ehi_s[2][32][EP];
    __shared__ f16 et_s[2][DM][TP];
    __shared__ f16 plds[4][16][40];

    half8 qf[8];
    const f16* qb = q_hi + ((size_t)(tt * 64 + wave * 16 + m_)) * DM + quad * 8;
#pragma unroll
    for (int s = 0; s < 8; ++s) qf[s] = *(const half8*)(qb + s * 32);

    floatx4 O[16];
#pragma unroll
    for (int i = 0; i < 16; ++i) { O[i][0]=0.f; O[i][1]=0.f; O[i][2]=0.f; O[i][3]=0.f; }
    float m1 = -INFINITY, m2 = -INFINITY, l = 0.f;
    int i1 = 0;

    const int ntile = (NVT - slice + NSLICE - 1) / NSLICE;

    half8 rA[4], rB[4];
    const int sr2 = lane >> 5, sc = lane & 31;
    const int dr = lane >> 2, vc = lane & 3;

    {
        const int v0 = slice * 32;
#pragma unroll
        for (int i = 0; i < 4; ++i) {
            int row = wave * 8 + i * 2 + sr2;
            rA[i] = *(const half8*)(e_hi + (size_t)(v0 + row) * DM + sc * 8);
        }
#pragma unroll
        for (int i = 0; i < 4; ++i) {
            int d = wave * 64 + i * 16 + dr;
            rB[i] = *(const half8*)(e_t + (size_t)d * VP + v0 + vc * 8);
        }
#pragma unroll
        for (int i = 0; i < 4; ++i) {
            int row = wave * 8 + i * 2 + sr2;
            *(half8*)&ehi_s[0][row][sc * 8] = rA[i];
        }
#pragma unroll
        for (int i = 0; i < 4; ++i) {
            int d = wave * 64 + i * 16 + dr;
            *(half8*)&et_s[0][d][vc * 8] = rB[i];
        }
    }
    __syncthreads();

    for (int it = 0; it < ntile; ++it) {
        const int b  = it & 1;
        const int v0 = (slice + it * NSLICE) * 32;
        const bool pre = (it + 1 < ntile);

        if (pre) {
            const int vn = v0 + NSLICE * 32;
#pragma unroll
            for (int i = 0; i < 4; ++i) {
                int row = wave * 8 + i * 2 + sr2;
                rA[i] = *(const half8*)(e_hi + (size_t)(vn + row) * DM + sc * 8);
            }
#pragma unroll
            for (int i = 0; i < 4; ++i) {
                int d = wave * 64 + i * 16 + dr;
                rB[i] = *(const half8*)(e_t + (size_t)d * VP + vn + vc * 8);
            }
        }

        floatx4 sf0, sf1;
        sf0[0]=0.f; sf0[1]=0.f; sf0[2]=0.f; sf0[3]=0.f;
        sf1[0]=0.f; sf1[1]=0.f; sf1[2]=0.f; sf1[3]=0.f;
#pragma unroll
        for (int s = 0; s < 8; ++s) {
            half8 a0 = *(const half8*)&ehi_s[b][m_][s * 32 + quad * 8];
            half8 a1 = *(const half8*)&ehi_s[b][m_ + 16][s * 32 + quad * 8];
            sf0 = __builtin_amdgcn_mfma_f32_16x16x32_f16(a0, qf[s], sf0, 0, 0, 0);
            sf1 = __builtin_amdgcn_mfma_f32_16x16x32_f16(a1, qf[s], sf1, 0, 0, 0);
        }
        if (v0 + 32 > VOCAB) {
#pragma unroll
            for (int r = 0; r < 4; ++r) {
                if (v0 + quad * 4 + r >= VOCAB)      sf0[r] = -INFINITY;
                if (v0 + 16 + quad * 4 + r >= VOCAB) sf1[r] = -INFINITY;
            }
        }

        float t1 = -INFINITY, t2 = -INFINITY; int ti = 0;
#pragma unroll
        for (int r = 0; r < 4; ++r) {
            float sv = sf0[r]; int vg = v0 + quad * 4 + r;
            t2 = fmaxf(t2, fminf(t1, sv));
            ti = (sv > t1) ? vg : ti;
            t1 = fmaxf(t1, sv);
        }
#pragma unroll
        for (int r = 0; r < 4; ++r) {
            float sv = sf1[r]; int vg = v0 + 16 + quad * 4 + r;
            t2 = fmaxf(t2, fminf(t1, sv));
            ti = (sv > t1) ? vg : ti;
            t1 = fmaxf(t1, sv);
        }
#pragma unroll
        for (int off = 16; off <= 32; off += 16) {
            float o1 = __shfl_xor(t1, off);
            float o2 = __shfl_xor(t2, off);
            int   oi = __shfl_xor(ti, off);
            t2 = fmaxf(fmaxf(t2, o2), fminf(t1, o1));
            ti = (o1 > t1) ? oi : ti;
            t1 = fmaxf(t1, o1);
        }

        float m1n = fmaxf(m1, t1);
        bool upd = (t1 > m1);
        m2 = fmaxf(fmaxf(m2, t2), fminf(m1, t1));
        i1 = upd ? ti : i1;
        if (__any(upd)) {
            float c = __expf(m1 - m1n);
            l *= c;
            float co[4];
#pragma unroll
            for (int r = 0; r < 4; ++r) co[r] = __shfl(c, (quad << 2) + r);
#pragma unroll
            for (int nt = 0; nt < 16; ++nt)
#pragma unroll
                for (int r = 0; r < 4; ++r) O[nt][r] *= co[r];
        }
        m1 = m1n;

        float p0[4], p1[4]; float ls = 0.f;
#pragma unroll
        for (int r = 0; r < 4; ++r) { float e = __expf(sf0[r] - m1n); p0[r] = e; ls += e; }
#pragma unroll
        for (int r = 0; r < 4; ++r) { float e = __expf(sf1[r] - m1n); p1[r] = e; ls += e; }
        ls += __shfl_xor(ls, 16);
        ls += __shfl_xor(ls, 32);
        l += ls;

        {
            half4v h0, h1;
#pragma unroll
            for (int r = 0; r < 4; ++r) { h0[r] = (f16)p0[r]; h1[r] = (f16)p1[r]; }
            *(half4v*)(&plds[wave][m_][quad * 4])      = h0;
            *(half4v*)(&plds[wave][m_][16 + quad * 4]) = h1;
        }
        __asm__ volatile("s_waitcnt lgkmcnt(0)" ::: "memory");
        half8 a2 = *(const half8*)(&plds[wave][m_][quad * 8]);

#pragma unroll
        for (int nt = 0; nt < 16; ++nt) {
            half8 b2 = *(const half8*)&et_s[b][nt * 16 + m_][quad * 8];
            O[nt] = __builtin_amdgcn_mfma_f32_16x16x32_f16(a2, b2, O[nt], 0, 0, 0);
        }

        if (pre) {
#pragma unroll
            for (int i = 0; i < 4; ++i) {
                int row = wave * 8 + i * 2 + sr2;
                *(half8*)&ehi_s[b ^ 1][row][sc * 8] = rA[i];
            }
#pragma unroll
            for (int i = 0; i < 4; ++i) {
                int d = wave * 64 + i * 16 + dr;
                *(half8*)&et_s[b ^ 1][d][vc * 8] = rB[i];
            }
        }
        __syncthreads();
    }

    const int trow0 = tt * 64 + wave * 16;
    float* ob = pO + ((size_t)slice * NROWS + trow0) * DM;
#pragma unroll
    for (int nt = 0; nt < 16; ++nt)
#pragma unroll
        for (int r = 0; r < 4; ++r)
            ob[(size_t)(quad * 4 + r) * DM + nt * 16 + m_] = O[nt][r];
    if (lane < 16) {
        const int idx = slice * NROWS + trow0 + lane;
        pm1[idx] = m1;
        pm2[idx] = m2;
        pl [idx] = l;
        pi1[idx] = i1;
    }
}

// ---------------------------------------------------------------------------
// Kernel 4: merge slices, approximate argmax + margin flags, decoder.
// ---------------------------------------------------------------------------
__global__ __launch_bounds__(256) void merge_decode(
    const float* __restrict__ pO, const float* __restrict__ pm1,
    const float* __restrict__ pm2, const float* __restrict__ pl,
    const int* __restrict__ pi1,
    const float* __restrict__ dec_w, const float* __restrict__ dec_b,
    float* __restrict__ out, float* __restrict__ amax_out,
    unsigned long long* __restrict__ amax64, int* flagcnt, int* flaglist,
    int* __restrict__ flbyte)
{
    const int tt  = blockIdx.x;
    const int tid = threadIdx.x;
    __shared__ float q_s[16][DM];
    __shared__ float sc[NSLICE][16];
    __shared__ float lI[16];

    if (tid < 16) {
        const int row = tt * 16 + tid;
        float M = -INFINITY, M2 = -INFINITY; int win = 0;
        for (int s = 0; s < NSLICE; ++s) {
            float v = pm1[s * NROWS + row];
            if (v > M) { M2 = M; M = v; win = s; }
            else M2 = fmaxf(M2, v);
        }
        for (int s = 0; s < NSLICE; ++s)
            M2 = fmaxf(M2, pm2[s * NROWS + row]);
        amax_out[row] = (float)pi1[win * NROWS + row];
        amax64[row] = 0ull;
        int fl = (M - M2) < MARGIN;
        flbyte[row] = fl;
        if (fl) {
            int pos = atomicAdd(flagcnt, 1);
            if (pos < FLAGCAP) flaglist[pos] = row;
        }
        float lt = 0.f;
        for (int s = 0; s < NSLICE; ++s) {
            float e = __expf(pm1[s * NROWS + row] - M);
            sc[s][tid] = e;
            lt += pl[s * NROWS + row] * e;
        }
        lI[tid] = 1.f / lt;
    }
    __syncthreads();
    {
        const int m = tid >> 4, d0 = (tid & 15) * 16;
        const int row = tt * 16 + m;
        for (int d = d0; d < d0 + 16; ++d) {
            float a = 0.f;
            for (int s = 0; s < NSLICE; ++s)
                a += pO[((size_t)s * NROWS + row) * DM + d] * sc[s][m];
            q_s[m][d] = a * lI[m];
        }
    }
    __syncthreads();
    {
        const int o = tid & 63;
        const float4* wp = (const float4*)(dec_w + (size_t)o * DM);
#pragma unroll
        for (int k = 0; k < 4; ++k) {
            const int m = (tid >> 6) + k * 4;
            const float4* qp = (const float4*)&q_s[m][0];
            float acc = 0.f;
            for (int d4 = 0; d4 < DM / 4; ++d4) {
                float4 w = wp[d4], q = qp[d4];
                acc += w.x * q.x + w.y * q.y + w.z * q.z + w.w * q.w;
            }
            out[(size_t)(tt * 16 + m) * OUTDIM + o] = acc + dec_b[o];
        }
    }
}

// ---------------------------------------------------------------------------
// Kernel 5a: pack flagged rows' q_hi/q_lo into a dense, coalesced buffer.
// qg[j] = [256 f16 hi | 256 f16 lo] for flagged row j.
// ---------------------------------------------------------------------------
__global__ __launch_bounds__(256) void gather_flagged(
    const f16* __restrict__ q_hi, const f16* __restrict__ q_lo,
    const int* __restrict__ flagcnt, const int* __restrict__ flaglist,
    f16* __restrict__ qg)
{
    int cnt = *flagcnt; if (cnt > FLAGCAP) cnt = FLAGCAP;
    const int j = blockIdx.x;
    if (j >= cnt) return;
    const int row = flaglist[j];
    const int t = threadIdx.x;
    qg[(size_t)j * 512 + t]       = q_hi[(size_t)row * DM + t];
    qg[(size_t)j * 512 + 256 + t] = q_lo[(size_t)row * DM + t];
}

// ---------------------------------------------------------------------------
// Kernel 5b: split-f16 MFMA recheck. logit = (e_hi+e_lo)·(q_hi+q_lo), all 4
// cross products -> error ~5e-7 (same scale as numpy's own fp32 noise).
// 1-wave blocks, 32 vocab rows each; per 16-flagged chunk: 64 MFMAs, then
// per-column top-1 reduction and one atomicMax per (f, block).
// ---------------------------------------------------------------------------
__global__ __launch_bounds__(64) void recheck_rows(
    const float* __restrict__ emb, const f16* __restrict__ qg,
    const int* __restrict__ flagcnt, const int* __restrict__ flaglist,
    unsigned long long* __restrict__ amax64)
{
    int cnt = *flagcnt; if (cnt > FLAGCAP) cnt = FLAGCAP;
    if (cnt == 0) return;
    const int v0   = blockIdx.x * 32;
    const int lane = threadIdx.x;
    const int m_   = lane & 15;
    const int quad = lane >> 4;

    __shared__ f16 ehi[32][EP];
    __shared__ f16 elo[32][EP];

    // stage 32 E rows fp32 -> (hi, lo): lane covers cols lane*4..lane*4+3
    for (int i = 0; i < 32; ++i) {
        const int v = v0 + i;
        float4 f = (v < VOCAB) ? *(const float4*)(emb + (size_t)v * DM + lane * 4)
                               : make_float4(0.f, 0.f, 0.f, 0.f);
        half4v hh, hl;
        hh[0]=(f16)f.x; hh[1]=(f16)f.y; hh[2]=(f16)f.z; hh[3]=(f16)f.w;
        hl[0]=(f16)(f.x-(float)hh[0]); hl[1]=(f16)(f.y-(float)hh[1]);
        hl[2]=(f16)(f.z-(float)hh[2]); hl[3]=(f16)(f.w-(float)hh[3]);
        *(half4v*)&ehi[i][lane * 4] = hh;
        *(half4v*)&elo[i][lane * 4] = hl;
    }
    __asm__ volatile("s_waitcnt lgkmcnt(0)" ::: "memory");

    for (int c0 = 0; c0 < cnt; c0 += 16) {
        const bool haveb = (c0 + m_) < cnt;
        const int fidx = haveb ? (c0 + m_) : 0;

        // B-frags (n = flagged index): lane m_ reads q row fidx
        half8 bh[8], bl[8];
        const f16* qb = qg + (size_t)fidx * 512 + quad * 8;
#pragma unroll
        for (int s = 0; s < 8; ++s) {
            bh[s] = *(const half8*)(qb + s * 32);
            bl[s] = *(const half8*)(qb + 256 + s * 32);
        }

        floatx4 C0, C1;
        C0[0]=0.f; C0[1]=0.f; C0[2]=0.f; C0[3]=0.f;
        C1[0]=0.f; C1[1]=0.f; C1[2]=0.f; C1[3]=0.f;
#pragma unroll
        for (int s = 0; s < 8; ++s) {
            half8 ah0 = *(const half8*)&ehi[m_][quad * 8 + 32 * s];
            half8 al0 = *(const half8*)&elo[m_][quad * 8 + 32 * s];
            half8 ah1 = *(const half8*)&ehi[m_ + 16][quad * 8 + 32 * s];
            half8 al1 = *(const half8*)&elo[m_ + 16][quad * 8 + 32 * s];
            C0 = __builtin_amdgcn_mfma_f32_16x16x32_f16(ah0, bh[s], C0, 0, 0, 0);
            C0 = __builtin_amdgcn_mfma_f32_16x16x32_f16(ah0, bl[s], C0, 0, 0, 0);
            C0 = __builtin_amdgcn_mfma_f32_16x16x32_f16(al0, bh[s], C0, 0, 0, 0);
            C0 = __builtin_amdgcn_mfma_f32_16x16x32_f16(al0, bl[s], C0, 0, 0, 0);
            C1 = __builtin_amdgcn_mfma_f32_16x16x32_f16(ah1, bh[s], C1, 0, 0, 0);
            C1 = __builtin_amdgcn_mfma_f32_16x16x32_f16(ah1, bl[s], C1, 0, 0, 0);
            C1 = __builtin_amdgcn_mfma_f32_16x16x32_f16(al1, bh[s], C1, 0, 0, 0);
            C1 = __builtin_amdgcn_mfma_f32_16x16x32_f16(al1, bl[s], C1, 0, 0, 0);
        }

        // top-1 over the 32 v rows of this block, per column f.
        // C layout: col = lane&15 (f), row = quad*4 + reg (v_local).
        float bv = -INFINITY; int bi = 0;
#pragma unroll
        for (int r = 0; r < 4; ++r) {
            int v = v0 + quad * 4 + r;
            float val = (v < VOCAB) ? C0[r] : -INFINITY;
            if (val > bv) { bv = val; bi = v; }
            int v2 = v + 16;
            float val2 = (v2 < VOCAB) ? C1[r] : -INFINITY;
            if (val2 > bv) { bv = val2; bi = v2; }
        }
#pragma unroll
        for (int off = 16; off <= 32; off += 16) {
            float ov = __shfl_xor(bv, off);
            int   oi = __shfl_xor(bi, off);
            if (ov > bv || (ov == bv && oi < bi)) { bv = ov; bi = oi; }
        }
        if (quad == 0 && haveb) {
            unsigned u = __float_as_uint(bv);
            u = (u & 0x80000000u) ? ~u : (u | 0x80000000u);
            unsigned long long key =
                ((unsigned long long)u << 32) | (unsigned)(~bi);
            atomicMax(&amax64[flaglist[fidx]], key);
        }
    }
}

__global__ void finalize_amax(const int* __restrict__ flbyte,
                              const unsigned long long* __restrict__ amax64,
                              float* __restrict__ amax_out)
{
    int row = blockIdx.x * 256 + threadIdx.x;
    if (row >= NROWS) return;
    if (flbyte[row]) {
        unsigned long long u = amax64[row];
        if (u) {
            unsigned idx = ~(unsigned)(u & 0xffffffffu);
            amax_out[row] = (float)idx;
        }
    }
}

// ---------------------------------------------------------------------------
// Fallback (round-1 VALU kernel) if ws_size is too small.
// ---------------------------------------------------------------------------
#define RPB 4
__global__ __launch_bounds__(256, 2) void fused_softmax_quant_kernel(
    const float* __restrict__ emb, const float* __restrict__ hs,
    const float* __restrict__ dec_w, const float* __restrict__ dec_b,
    float* __restrict__ out, float* __restrict__ amax_out)
{
    const int tid  = threadIdx.x;
    const int g    = tid >> 4;
    const int q    = tid & 15;
    const int row0 = blockIdx.x * RPB;

    __shared__ __align__(16) float q_lds[RPB][DM];
    __shared__ float sm[16][RPB], sl[16][RPB];
    __shared__ int   sam[16][RPB];
    __shared__ float sLf[RPB];

    for (int i = tid; i < RPB * DM; i += 256) (&q_lds[0][0])[i] = 0.f;

    float4 hsr[RPB][4];
#pragma unroll
    for (int r = 0; r < RPB; ++r)
#pragma unroll
        for (int o = 0; o < 4; ++o)
            hsr[r][o] = *(const float4*)(hs + (size_t)(row0 + r) * DM + o * 64 + q * 4);

    float m[RPB], l[RPB];
    int   am[RPB];
    float4 acc[RPB][4];
#pragma unroll
    for (int r = 0; r < RPB; ++r) {
        m[r] = -INFINITY; l[r] = 0.f; am[r] = 0;
#pragma unroll
        for (int o = 0; o < 4; ++o) acc[r][o] = make_float4(0.f, 0.f, 0.f, 0.f);
    }

    float ecur[16], enxt[16];
    {
        size_t b0 = (size_t)g * DM + q * 4;
#pragma unroll
        for (int o = 0; o < 4; ++o)
            *(float4*)(enxt + o * 4) = *(const float4*)(emb + b0 + o * 64);
    }

#pragma unroll 1
    for (int v = g; v < VOCAB; v += 16) {
#pragma unroll
        for (int j = 0; j < 16; ++j) ecur[j] = enxt[j];
        int vn = (v + 16 < VOCAB) ? v + 16 : v;
        size_t bn = (size_t)vn * DM + q * 4;
#pragma unroll
        for (int o = 0; o < 4; ++o)
            *(float4*)(enxt + o * 4) = *(const float4*)(emb + bn + o * 64);

        float part[RPB];
#pragma unroll
        for (int r = 0; r < RPB; ++r) {
            const float* hp = (const float*)&hsr[r][0];
            float t = 0.f;
#pragma unroll
            for (int j = 0; j < 16; ++j) t += ecur[j] * hp[j];
            part[r] = t;
        }
#pragma unroll
        for (int mask = 8; mask >= 1; mask >>= 1)
#pragma unroll
            for (int r = 0; r < RPB; ++r)
                part[r] += __shfl_xor(part[r], mask, 16);

#pragma unroll
        for (int r = 0; r < RPB; ++r) {
            float lg = part[r];
            float* ap = (float*)&acc[r][0];
            if (lg > m[r]) {
                float c = __expf(m[r] - lg);
                m[r] = lg; am[r] = v;
                l[r] = l[r] * c + 1.f;
#pragma unroll
                for (int j = 0; j < 16; ++j) ap[j] = ap[j] * c + ecur[j];
            } else {
                float p = __expf(lg - m[r]);
                l[r] += p;
#pragma unroll
                for (int j = 0; j < 16; ++j) ap[j] += p * ecur[j];
            }
        }
    }

    if (q == 0) {
#pragma unroll
        for (int r = 0; r < RPB; ++r) { sm[g][r] = m[r]; sl[g][r] = l[r]; sam[g][r] = am[r]; }
    }
    __syncthreads();

    float wgt[RPB], Lr[RPB];
    int   A[RPB];
#pragma unroll
    for (int r = 0; r < RPB; ++r) {
        float M = -INFINITY; int a = 0;
        for (int gg = 0; gg < 16; ++gg) {
            float mv = sm[gg][r];
            if (mv > M) { M = mv; a = sam[gg][r]; }
        }
        float L = 0.f;
        for (int gg = 0; gg < 16; ++gg) L += sl[gg][r] * __expf(sm[gg][r] - M);
        wgt[r] = __expf(m[r] - M);
        Lr[r] = L; A[r] = a;
    }

#pragma unroll
    for (int r = 0; r < RPB; ++r) {
        const float* ap = (const float*)&acc[r][0];
#pragma unroll
        for (int j = 0; j < 16; ++j) {
            float vs = ap[j] * wgt[r];
            vs += __shfl_xor(vs, 16, 64);
            vs += __shfl_xor(vs, 32, 64);
            if ((g & 3) == 0) {
                int o = j >> 2, c = j & 3;
                atomicAdd(&q_lds[r][o * 64 + q * 4 + c], vs);
            }
        }
    }
    if (tid == 0) {
#pragma unroll
        for (int r = 0; r < RPB; ++r) {
            sLf[r] = Lr[r];
            amax_out[row0 + r] = (float)A[r];
        }
    }
    __syncthreads();

    {
        const int r = tid >> 6, o = tid & 63;
        const float4* dwp = (const float4*)(dec_w + (size_t)o * DM);
        const float4* qp  = (const float4*)&q_lds[r][0];
        float s = 0.f;
#pragma unroll 8
        for (int d4 = 0; d4 < DM / 4; ++d4) {
            float4 wv = dwp[d4];
            float4 qv = qp[d4];
            s += wv.x * qv.x + wv.y * qv.y + wv.z * qv.z + wv.w * qv.w;
        }
        s = s / sLf[r] + dec_b[o];
        out[(size_t)(row0 + r) * OUTDIM + o] = s;
    }
}

extern "C" void kernel_launch(void* const* d_in, const int* in_sizes, int n_in,
                              void* d_out, int out_size, void* d_ws, size_t ws_size,
                              hipStream_t stream)
{
    const float* x     = (const float*)d_in[0];
    const float* emb   = (const float*)d_in[1];
    const float* wpe   = (const float*)d_in[2];
    const float* enc_w = (const float*)d_in[3];
    const float* enc_b = (const float*)d_in[4];
    const float* ln_g  = (const float*)d_in[5];
    const float* ln_b  = (const float*)d_in[6];
    const float* dec_w = (const float*)d_in[7];
    const float* dec_b = (const float*)d_in[8];

    float* out      = (float*)d_out;
    float* amax_out = out + (size_t)NROWS * OUTDIM;

    char* w = (char*)d_ws;
    size_t off = 0;
    float* hs = (float*)(w + off);          off += (size_t)NROWS * DM * 4;
    f16* q_hi = (f16*)(w + off);            off += (size_t)NROWS * DM * 2;
    f16* q_lo = (f16*)(w + off);            off += (size_t)NROWS * DM * 2;
    f16* e_hi = (f16*)(w + off);            off += (size_t)VP * DM * 2;
    f16* e_t  = (f16*)(w + off);            off += (size_t)DM * VP * 2;
    float* pO = (float*)(w + off);          off += (size_t)NSLICE * NROWS * DM * 4;
    float* pm1 = (float*)(w + off);         off += (size_t)NSLICE * NROWS * 4;
    float* pm2 = (float*)(w + off);         off += (size_t)NSLICE * NROWS * 4;
    float* pl  = (float*)(w + off);         off += (size_t)NSLICE * NROWS * 4;
    int*   pi1 = (int*)(w + off);           off += (size_t)NSLICE * NROWS * 4;
    unsigned long long* amax64 = (unsigned long long*)(w + off); off += (size_t)NROWS * 8;
    int* flagcnt  = (int*)(w + off);        off += 256;
    int* flaglist = (int*)(w + off);        off += FLAGCAP * 4;
    int* flbyte   = (int*)(w + off);        off += (size_t)NROWS * 4;
    f16* qg       = (f16*)(w + off);        off += (size_t)FLAGCAP * 512 * 2;

    const bool full = (ws_size >= off);

    encode_ln_kernel<<<NROWS, 256, 0, stream>>>(x, enc_w, enc_b, wpe, ln_g, ln_b,
                                                hs, q_hi, q_lo, flagcnt, full ? 1 : 0);
    if (full) {
        prep_emb<<<(VP + 127) / 128, 256, 0, stream>>>(emb, e_hi, e_t);
        fused_main<<<NTT * NSLICE, 256, 0, stream>>>(e_hi, e_t, q_hi,
                                                     pO, pm1, pm2, pl, pi1);
        merge_decode<<<NROWS / 16, 256, 0, stream>>>(pO, pm1, pm2, pl, pi1, dec_w, dec_b,
                                                     out, amax_out, amax64, flagcnt,
                                                     flaglist, flbyte);
        gather_flagged<<<FLAGCAP, 256, 0, stream>>>(q_hi, q_lo, flagcnt, flaglist, qg);
        recheck_rows<<<NVT, 64, 0, stream>>>(emb, qg, flagcnt, flaglist, amax64);
        finalize_amax<<<(NROWS + 255) / 256, 256, 0, stream>>>(flbyte, amax64, amax_out);
    } else {
        fused_softmax_quant_kernel<<<NROWS / RPB, 256, 0, stream>>>(emb, hs, dec_w,
                                                                    dec_b, out, amax_out);
    }
}